// Round 7
// baseline (3298.788 us; speedup 1.0000x reference)
//
#include <hip/hip_runtime.h>
#include <hip/hip_cooperative_groups.h>
namespace cg = cooperative_groups;

// Problem constants
constexpr int kB  = 1024;
constexpr int kT  = 512;
constexpr int kF  = 32;
constexpr int kE  = 16;
constexpr int kH  = 128;
constexpr int kMB = 16;             // batches per block (MFMA M)
constexpr int kNMB = kB / kMB;      // 64 batch tiles
constexpr int kTc = 32;             // chunk length (back to the R5 optimum)
constexpr int kNCh = kT / kTc;      // 16 chunks
constexpr int kTg = kTc / 2;        // t-steps per GEMM block
constexpr size_t kH0Str = (size_t)kB * kTc * kH;     // u32 per h0 chunk buffer
constexpr size_t kSlots = (size_t)kNMB * kTc * 512;  // gx lane-slots per chunk
constexpr size_t kGx0Str = kSlots * 12;              // u32 per gx0 chunk buffer

typedef __attribute__((ext_vector_type(8))) _Float16 f16x8;
typedef __attribute__((ext_vector_type(4))) _Float16 f16x4;
typedef __attribute__((ext_vector_type(4))) float    f32x4;

#define MFMA16(a,b,c) __builtin_amdgcn_mfma_f32_16x16x32_f16(a,b,c,0,0,0)

__device__ __forceinline__ float sigm_hw(float x){
    float e = __builtin_amdgcn_exp2f(-1.442695041f * x);
    return __builtin_amdgcn_rcpf(1.0f + e);
}
__device__ __forceinline__ float tanh_hw(float x){
    float e = __builtin_amdgcn_exp2f(-2.885390082f * x);
    return fmaf(2.0f, __builtin_amdgcn_rcpf(1.0f + e), -1.0f);
}
__device__ __forceinline__ void splitF(float v, _Float16 &hi, _Float16 &lo){
    hi = (_Float16)v;
    lo = (_Float16)(v - (float)hi);
}
__device__ __forceinline__ f16x8 loadW8(const float* __restrict__ p){
    f16x8 r;
#pragma unroll
    for (int j=0;j<8;j++) r[j] = (_Float16)p[j];
    return r;
}
__device__ __forceinline__ unsigned short f2u(_Float16 h){ return __builtin_bit_cast(unsigned short, h); }
__device__ __forceinline__ _Float16 u2f(unsigned short u){ return __builtin_bit_cast(_Float16, u); }
__device__ __forceinline__ unsigned pack2(float a, float b){
    return (unsigned)f2u((_Float16)a) | ((unsigned)f2u((_Float16)b) << 16);
}
__device__ __forceinline__ float uf(unsigned u){ return __builtin_bit_cast(float, u); }
// LDS-only barrier: drains ds ops (lgkmcnt) but leaves global loads/stores in
// flight across the barrier. The compiler still inserts vmcnt waits before
// register USES of prefetched data; cross-role ordering comes from grid.sync.
__device__ __forceinline__ void bar_lds(){
    asm volatile("s_waitcnt lgkmcnt(0)\n\ts_barrier" ::: "memory");
}

// LDS: h planes row-major [m][k] (136 = 128 + 8 pad). Double buffered; one
// lgkm-barrier per step.
struct SRec {
    alignas(16) _Float16 hH[2][16][136];
    alignas(16) _Float16 hL[2][16][136];
    alignas(16) float hf[16][132];         // head scratch
    alignas(16) float hf2[16][132];
};
struct SGem {
    alignas(16) _Float16 aH[2][16][136];
    alignas(16) _Float16 aL[2][16][136];
};
union SU { SRec r; SGem g; };

struct G3 { uint4 r, z, n; };   // f32 gx0 slot (48B)

// ---------------------------------------------------------------------------
// PERSISTENT cooperative kernel (R7). R5/R6 fit: step s=1.27us, per-dispatch
// overhead P=16us -> ~300us of the 1077 was launch+prologue repetition. One
// launch, 256 blocks x 512 threads (1 block/CU, 8 waves, 2/SIMD — the R2
// optimum), the chunk pipeline loop runs INSIDE with grid.sync() replacing
// dispatch boundaries (+ __threadfence both sides for cross-XCD visibility).
// Hoisted out of the loop (previously repeated 19x): weight loads (~290
// scalar loads/thread), emb/bias init, stream-prologue latency. New: L0/L1
// hidden state persists in registers/LDS across chunks (h1state deleted;
// L0's chunk-boundary h reload deleted — persisted hreg is the exact f32 h).
// Roles per iteration c = -1..kNCh+1:
//   blocks   0..63 : layer-0 GRU chunk c           (the serial pole)
//   blocks 64..191 : gx1 GEMM chunk c-1  AND  gx0 GEMM chunk c+1
//   blocks 192..255: layer-1 GRU chunk c-2 (+head on last)
// gx0[t] = Wih0·[x_t,emb] + bih0 + bhh0(r,z) (f32, exact); L0 inits r/z
// accumulators directly from the loaded uint4. hi/lo MFMA chains accumulate
// in independent 4-deep chains (R6, neutral-but-harmless).
// In-lane gate update via MFMA C-layout: lane (lq,lm) reg q owns element
// (m=lq*4+q, i=16w+lm) of every gate tile simultaneously.
// ---------------------------------------------------------------------------
__attribute__((amdgpu_waves_per_eu(2, 2)))
__global__ void __launch_bounds__(512) rnn_persist(
    const float* __restrict__ x, const int* __restrict__ tick,
    const float* __restrict__ embed,
    const float* __restrict__ Wih0, const float* __restrict__ Whh0,
    const float* __restrict__ bih0, const float* __restrict__ bhh0,
    const float* __restrict__ Wih1, const float* __restrict__ bih1,
    const float* __restrict__ Whh1, const float* __restrict__ bhh1,
    const float* __restrict__ hw1, const float* __restrict__ hb1,
    const float* __restrict__ hw2, const float* __restrict__ hb2,
    unsigned* __restrict__ h0seq, unsigned* __restrict__ gxA,
    unsigned* __restrict__ gxB, unsigned* __restrict__ gx0,
    float* __restrict__ out)
{
    __shared__ SU sm;
    cg::grid_group grid = cg::this_grid();
    const int tid = threadIdx.x;
    const int w = tid >> 6, l = tid & 63, lm = l & 15, lq = l >> 4;
    const int i = 16*w + lm;                    // owned gate/hidden column
    const int cls[3] = { i, 128 + i, 256 + i }; // r/z/n weight rows

    if (blockIdx.x < 64) {
        // ================= layer-0 recurrence (persistent) =================
        SRec &S = sm.r;
        const int mb = blockIdx.x;
        f16x8 wv[3][4];
#pragma unroll
        for (int T=0; T<3; T++)
#pragma unroll
            for (int kt=0; kt<4; kt++)
                wv[T][kt] = loadW8(Whh0 + (size_t)cls[T]*kH + kt*32 + lq*8);
        const float bn = bhh0[cls[2]];

        float hreg[4];
#pragma unroll
        for (int q=0;q<4;q++){
            hreg[q]=0.f;
            S.hH[0][lq*4+q][i]=(_Float16)0.f;
            S.hL[0][lq*4+q][i]=(_Float16)0.f;
        }
        const size_t base = (size_t)mb*kTc*512 + tid;
        int buf = 0;
        for (int c = -1; c <= kNCh+1; ++c){
            if (c >= 0 && c < kNCh){
                unsigned* h0w = h0seq + (size_t)(c & 1) * kH0Str;
                const unsigned* g0 = gx0 + (size_t)(c & 1) * kGx0Str;
                auto ld3 = [&](size_t slot){
                    G3 g; const unsigned* p = g0 + slot*12;
                    g.r = *(const uint4*)p; g.z = *(const uint4*)(p+4); g.n = *(const uint4*)(p+8);
                    return g;
                };
                G3 gc = ld3(base), gn = ld3(base + 512);
                bar_lds();
                for (int tc=0; tc<kTc; tc++){
                    const int nb = buf ^ 1;
                    f16x8 aHf[4], aLf[4];
#pragma unroll
                    for (int kt=0;kt<4;kt++){
                        aHf[kt] = *(const f16x8*)&S.hH[buf][lm][kt*32 + lq*8];
                        aLf[kt] = *(const f16x8*)&S.hL[buf][lm][kt*32 + lq*8];
                    }
                    // r/z start from gx0 (biases pre-folded); hi/lo planes in
                    // independent 4-deep chains
                    f32x4 aR  = __builtin_bit_cast(f32x4, gc.r);
                    f32x4 aZ  = __builtin_bit_cast(f32x4, gc.z);
                    f32x4 aNH = {bn,bn,bn,bn};
                    f32x4 aRl = {0.f,0.f,0.f,0.f};
                    f32x4 aZl = {0.f,0.f,0.f,0.f};
                    f32x4 aNl = {0.f,0.f,0.f,0.f};
#pragma unroll
                    for (int kt=0;kt<4;kt++){
                        aR =MFMA16(aHf[kt],wv[0][kt],aR);  aRl=MFMA16(aLf[kt],wv[0][kt],aRl);
                        aZ =MFMA16(aHf[kt],wv[1][kt],aZ);  aZl=MFMA16(aLf[kt],wv[1][kt],aZl);
                        aNH=MFMA16(aHf[kt],wv[2][kt],aNH); aNl=MFMA16(aLf[kt],wv[2][kt],aNl);
                    }
                    aR += aRl; aZ += aZl; aNH += aNl;
                    const float nx[4] = { uf(gc.n.x), uf(gc.n.y), uf(gc.n.z), uf(gc.n.w) };
                    unsigned pk[4];
#pragma unroll
                    for (int q=0;q<4;q++){
                        float r = sigm_hw(aR[q]);
                        float z = sigm_hw(aZ[q]);
                        float n = tanh_hw(fmaf(r, aNH[q], nx[q]));
                        float h = fmaf(z, hreg[q]-n, n);
                        hreg[q] = h;
                        _Float16 hh,hl; splitF(h,hh,hl);
                        S.hH[nb][lq*4+q][i]=hh;
                        S.hL[nb][lq*4+q][i]=hl;
                        pk[q] = ((unsigned)f2u(hh)<<16) | f2u(hl);
                    }
#pragma unroll
                    for (int q=0;q<4;q++)
                        h0w[((size_t)(mb*kTc + tc)*16 + lq*4+q)*kH + i] = pk[q];
                    gc = gn;
                    int tn = tc + 2; if (tn > kTc-1) tn = kTc-1;
                    gn = ld3(base + (size_t)tn*512);
                    bar_lds();
                    buf = nb;
                }
            }
            if (c <= kNCh){ __threadfence(); grid.sync(); __threadfence(); }
        }
    } else if (blockIdx.x < 192) {
        // ============ gx GEMM blocks (persistent weights/init) ============
        const int bid = blockIdx.x - 64;
        const int mb = bid >> 1, t0 = (bid & 1) * kTg;
        const int b0 = mb * kMB;
        SGem &S = sm.g;
        // gx1 weights + biases (hoisted)
        f16x8 wv1[3][4]; float bI[3];
#pragma unroll
        for (int T=0; T<3; T++){
#pragma unroll
            for (int kt=0; kt<4; kt++)
                wv1[T][kt] = loadW8(Wih1 + (size_t)cls[T]*kH + kt*32 + lq*8);
            bI[T] = bih1[cls[T]];
        }
        // gx0 weights + emb/bias init (hoisted). r/z carry bih0+bhh0 folded.
        f16x8 xw[3];
#pragma unroll
        for (int T=0; T<3; T++)
            xw[T] = loadW8(Wih0 + (size_t)cls[T]*48 + lq*8);
        float ini[3][4];
        {
            const float bi0 = bih0[cls[0]] + bhh0[cls[0]];
            const float bi1 = bih0[cls[1]] + bhh0[cls[1]];
            const float bi2 = bih0[cls[2]];
            const float* w0 = Wih0 + (size_t)cls[0]*48 + 32;
            const float* w1 = Wih0 + (size_t)cls[1]*48 + 32;
            const float* w2 = Wih0 + (size_t)cls[2]*48 + 32;
#pragma unroll
            for (int q=0; q<4; q++){
                const float* ep = embed + (size_t)tick[b0 + lq*4 + q] * kE;
                float s0=0.f, s1=0.f, s2=0.f;
#pragma unroll
                for (int e=0; e<kE; e++){
                    float ev = ep[e];
                    s0 = fmaf(ev, w0[e], s0);
                    s1 = fmaf(ev, w1[e], s1);
                    s2 = fmaf(ev, w2[e], s2);
                }
                ini[0][q]=bi0+s0; ini[1][q]=bi1+s1; ini[2][q]=bi2+s2;
            }
        }
        const int sr = tid >> 5, sq = tid & 31;   // staging role: row, u32-quad

        for (int c = -1; c <= kNCh+1; ++c){
            const int g = c - 1;
            if (g >= 0 && g < kNCh) {
                const unsigned* h0r = h0seq + (size_t)(g & 1) * kH0Str;
                unsigned* gA = gxA + (size_t)(g & 1) * kSlots * 4;
                unsigned* gB = gxB + (size_t)(g & 1) * kSlots * 2;
                auto ld = [&](int t){
                    return *(const uint4*)(h0r + ((size_t)(mb*kTc + t)*16 + sr)*kH + 4*sq);
                };
                auto stage = [&](int bf, uint4 u){
                    f16x4 vh = { u2f((unsigned short)(u.x>>16)), u2f((unsigned short)(u.y>>16)),
                                 u2f((unsigned short)(u.z>>16)), u2f((unsigned short)(u.w>>16)) };
                    f16x4 vl = { u2f((unsigned short)u.x), u2f((unsigned short)u.y),
                                 u2f((unsigned short)u.z), u2f((unsigned short)u.w) };
                    *(f16x4*)&S.aH[bf][sr][4*sq] = vh;
                    *(f16x4*)&S.aL[bf][sr][4*sq] = vl;
                };
                stage(0, ld(t0));
                uint4 nxt = ld(t0 + 1);
                bar_lds();
                for (int tt=0; tt<kTg; tt++){
                    const int t = t0 + tt, bf = tt & 1;
                    f16x8 fH[4], fL[4];
#pragma unroll
                    for (int kt=0;kt<4;kt++){
                        fH[kt] = *(const f16x8*)&S.aH[bf][lm][kt*32 + lq*8];
                        fL[kt] = *(const f16x8*)&S.aL[bf][lm][kt*32 + lq*8];
                    }
                    if (tt+1 < kTg) stage(bf^1, nxt);
                    if (tt+2 < kTg) nxt = ld(t0 + tt + 2);
                    f32x4 aR = {bI[0],bI[0],bI[0],bI[0]};
                    f32x4 aZ = {bI[1],bI[1],bI[1],bI[1]};
                    f32x4 aN = {bI[2],bI[2],bI[2],bI[2]};
#pragma unroll
                    for (int kt=0;kt<4;kt++){
                        aR=MFMA16(fH[kt],wv1[0][kt],aR); aR=MFMA16(fL[kt],wv1[0][kt],aR);
                        aZ=MFMA16(fH[kt],wv1[1][kt],aZ); aZ=MFMA16(fL[kt],wv1[1][kt],aZ);
                        aN=MFMA16(fH[kt],wv1[2][kt],aN); aN=MFMA16(fL[kt],wv1[2][kt],aN);
                    }
                    const size_t slot = ((size_t)mb*kTc + t)*512 + tid;
                    *(uint4*)(gA + slot*4) = make_uint4(pack2(aR[0],aR[1]), pack2(aR[2],aR[3]),
                                                        pack2(aZ[0],aZ[1]), pack2(aZ[2],aZ[3]));
                    *(uint2*)(gB + slot*2) = make_uint2(pack2(aN[0],aN[1]), pack2(aN[2],aN[3]));
                    bar_lds();
                }
            }
            const int p = c + 1;
            if (p >= 0 && p < kNCh) {
                unsigned* g0w = gx0 + (size_t)(p & 1) * kGx0Str;
                for (int tt=0; tt<kTg; tt++){
                    const int t = t0 + tt;
                    const float* xp = x + (size_t)(b0+lm)*kT*kF + (size_t)(p*kTc + t)*kF + lq*8;
                    const float4 xa = *(const float4*)xp;
                    const float4 xb = *(const float4*)(xp + 4);
                    const float xv[8] = { xa.x, xa.y, xa.z, xa.w, xb.x, xb.y, xb.z, xb.w };
                    f16x8 xH, xL;
#pragma unroll
                    for (int j=0;j<8;j++){
                        _Float16 hh,hl; splitF(xv[j],hh,hl);
                        xH[j]=hh; xL[j]=hl;
                    }
                    f32x4 aR = {ini[0][0],ini[0][1],ini[0][2],ini[0][3]};
                    f32x4 aZ = {ini[1][0],ini[1][1],ini[1][2],ini[1][3]};
                    f32x4 aN = {ini[2][0],ini[2][1],ini[2][2],ini[2][3]};
                    aR=MFMA16(xH,xw[0],aR); aR=MFMA16(xL,xw[0],aR);
                    aZ=MFMA16(xH,xw[1],aZ); aZ=MFMA16(xL,xw[1],aZ);
                    aN=MFMA16(xH,xw[2],aN); aN=MFMA16(xL,xw[2],aN);
                    const size_t slot = ((size_t)mb*kTc + t)*512 + tid;
                    *(uint4*)(g0w + slot*12)     = __builtin_bit_cast(uint4, aR);
                    *(uint4*)(g0w + slot*12 + 4) = __builtin_bit_cast(uint4, aZ);
                    *(uint4*)(g0w + slot*12 + 8) = __builtin_bit_cast(uint4, aN);
                }
            }
            if (c <= kNCh){ __threadfence(); grid.sync(); __threadfence(); }
        }
    } else {
        // ================= layer-1 recurrence (persistent) =================
        SRec &S = sm.r;
        const int mb = blockIdx.x - 192, b0 = mb * kMB;
        f16x8 wv[3][4];
#pragma unroll
        for (int T=0; T<3; T++)
#pragma unroll
            for (int kt=0; kt<4; kt++)
                wv[T][kt] = loadW8(Whh1 + (size_t)cls[T]*kH + kt*32 + lq*8);
        const float br = bhh1[cls[0]], bz = bhh1[cls[1]], bn = bhh1[cls[2]];

        float hreg[4];
        const size_t base = (size_t)mb*kTc*512 + tid;
        int buf = 0;
        for (int c = -1; c <= kNCh+1; ++c){
            const int e0 = c - 2;
            if (e0 >= 0 && e0 < kNCh){
                if (e0 == 0){
                    buf = 0;
#pragma unroll
                    for (int q=0;q<4;q++){
                        hreg[q]=0.f;
                        S.hH[0][lq*4+q][i]=(_Float16)0.f;
                        S.hL[0][lq*4+q][i]=(_Float16)0.f;
                    }
                }
                const unsigned* gA = gxA + (size_t)(e0 & 1) * kSlots * 4;
                const unsigned* gB = gxB + (size_t)(e0 & 1) * kSlots * 2;
                uint4 g4c = *(const uint4*)(gA + base*4);
                uint2 g2c = *(const uint2*)(gB + base*2);
                uint4 g4n = *(const uint4*)(gA + (base + 512)*4);
                uint2 g2n = *(const uint2*)(gB + (base + 512)*2);
                bar_lds();
                for (int tc=0; tc<kTc; tc++){
                    const int nb = buf ^ 1;
                    f16x8 aHf[4], aLf[4];
#pragma unroll
                    for (int kt=0;kt<4;kt++){
                        aHf[kt] = *(const f16x8*)&S.hH[buf][lm][kt*32 + lq*8];
                        aLf[kt] = *(const f16x8*)&S.hL[buf][lm][kt*32 + lq*8];
                    }
                    f32x4 aR={br,br,br,br}, aZ={bz,bz,bz,bz}, aNH={bn,bn,bn,bn};
                    f32x4 aRl={0.f,0.f,0.f,0.f}, aZl={0.f,0.f,0.f,0.f}, aNl={0.f,0.f,0.f,0.f};
#pragma unroll
                    for (int kt=0;kt<4;kt++){
                        aR =MFMA16(aHf[kt],wv[0][kt],aR);  aRl=MFMA16(aLf[kt],wv[0][kt],aRl);
                        aZ =MFMA16(aHf[kt],wv[1][kt],aZ);  aZl=MFMA16(aLf[kt],wv[1][kt],aZl);
                        aNH=MFMA16(aHf[kt],wv[2][kt],aNH); aNl=MFMA16(aLf[kt],wv[2][kt],aNl);
                    }
                    aR += aRl; aZ += aZl; aNH += aNl;
                    const float rx[4] = { (float)u2f((unsigned short)g4c.x), (float)u2f((unsigned short)(g4c.x>>16)),
                                          (float)u2f((unsigned short)g4c.y), (float)u2f((unsigned short)(g4c.y>>16)) };
                    const float zx[4] = { (float)u2f((unsigned short)g4c.z), (float)u2f((unsigned short)(g4c.z>>16)),
                                          (float)u2f((unsigned short)g4c.w), (float)u2f((unsigned short)(g4c.w>>16)) };
                    const float nx[4] = { (float)u2f((unsigned short)g2c.x), (float)u2f((unsigned short)(g2c.x>>16)),
                                          (float)u2f((unsigned short)g2c.y), (float)u2f((unsigned short)(g2c.y>>16)) };
#pragma unroll
                    for (int q=0;q<4;q++){
                        float r = sigm_hw(aR[q] + rx[q]);
                        float z = sigm_hw(aZ[q] + zx[q]);
                        float n = tanh_hw(fmaf(r, aNH[q], nx[q]));
                        float h = fmaf(z, hreg[q]-n, n);
                        hreg[q] = h;
                        _Float16 hh,hl; splitF(h,hh,hl);
                        S.hH[nb][lq*4+q][i]=hh;
                        S.hL[nb][lq*4+q][i]=hl;
                    }
                    g4c = g4n; g2c = g2n;
                    int tn = tc + 2; if (tn > kTc-1) tn = kTc-1;
                    g4n = *(const uint4*)(gA + (base + (size_t)tn*512)*4);
                    g2n = *(const uint2*)(gB + (base + (size_t)tn*512)*2);
                    bar_lds();
                    buf = nb;
                }
                if (e0 == kNCh-1){
                    // head: hid = relu(h1 @ hw1^T + hb1); y = hid @ hw2^T + hb2
#pragma unroll
                    for (int q=0;q<4;q++) S.hf[lq*4+q][i] = hreg[q];
                    __syncthreads();
                    const int hm = tid >> 5, i0 = (tid & 31) * 4;
#pragma unroll
                    for (int e=0;e<4;e++){
                        const float* wr = hw1 + (size_t)(i0+e)*kH;
                        float s = hb1[i0+e];
                        for (int k2=0;k2<kH;k2++) s = fmaf(wr[k2], S.hf[hm][k2], s);
                        S.hf2[hm][i0+e] = fmaxf(s, 0.f);
                    }
                    __syncthreads();
                    if (tid < kMB){
                        float s = hb2[0];
                        for (int k2=0;k2<kH;k2++) s = fmaf(S.hf2[tid][k2], hw2[k2], s);
                        out[b0 + tid] = s;
                    }
                }
            }
            if (c <= kNCh){ __threadfence(); grid.sync(); __threadfence(); }
        }
    }
}

extern "C" void kernel_launch(void* const* d_in, const int* in_sizes, int n_in,
                              void* d_out, int out_size, void* d_ws, size_t ws_size,
                              hipStream_t stream)
{
    const float* x     = (const float*)d_in[0];
    const int*   tick  = (const int*)d_in[1];
    const float* embed = (const float*)d_in[2];
    const float* Wih0  = (const float*)d_in[3];
    const float* Whh0  = (const float*)d_in[4];
    const float* bih0  = (const float*)d_in[5];
    const float* bhh0  = (const float*)d_in[6];
    const float* Wih1  = (const float*)d_in[7];
    const float* Whh1  = (const float*)d_in[8];
    const float* bih1  = (const float*)d_in[9];
    const float* bhh1  = (const float*)d_in[10];
    const float* hw1   = (const float*)d_in[11];
    const float* hb1   = (const float*)d_in[12];
    const float* hw2   = (const float*)d_in[13];
    const float* hb2   = (const float*)d_in[14];
    float* out = (float*)d_out;

    // ws: h0seq 2x16.8MB | gxA 2x16.8MB | gxB 2x8.4MB | gx0 2x50.3MB ~ 184MB
    unsigned* h0seq = (unsigned*)d_ws;
    unsigned* gxA   = h0seq + 2*kH0Str;
    unsigned* gxB   = gxA + 2*kSlots*4;
    unsigned* gx0   = gxB + 2*kSlots*2;

    void* args[] = {
        (void*)&x, (void*)&tick, (void*)&embed,
        (void*)&Wih0, (void*)&Whh0, (void*)&bih0, (void*)&bhh0,
        (void*)&Wih1, (void*)&bih1, (void*)&Whh1, (void*)&bhh1,
        (void*)&hw1, (void*)&hb1, (void*)&hw2, (void*)&hb2,
        (void*)&h0seq, (void*)&gxA, (void*)&gxB, (void*)&gx0, (void*)&out
    };
    hipLaunchCooperativeKernel((void*)rnn_persist, dim3(256), dim3(512),
                               args, 0, stream);
}

// Round 8
// 1052.722 us; speedup vs baseline: 3.1336x; 3.1336x over previous
//
#include <hip/hip_runtime.h>

// Problem constants
constexpr int kB  = 1024;
constexpr int kT  = 512;
constexpr int kF  = 32;
constexpr int kE  = 16;
constexpr int kH  = 128;
constexpr int kMB = 16;             // batches per block (MFMA M)
constexpr int kNMB = kB / kMB;      // 64 batch tiles
constexpr int kTc = 32;             // chunk length (measured optimum)
constexpr int kNCh = kT / kTc;      // 16 chunks
constexpr int kTg = kTc / 2;        // t-steps per GEMM block
constexpr size_t kH0Str = (size_t)kB * kTc * kH;     // u32 per h0 chunk buffer
constexpr size_t kSlots = (size_t)kNMB * kTc * 512;  // gx lane-slots per chunk
constexpr size_t kGx0Str = kSlots * 12;              // u32 per gx0 chunk buffer

typedef __attribute__((ext_vector_type(8))) _Float16 f16x8;
typedef __attribute__((ext_vector_type(4))) _Float16 f16x4;
typedef __attribute__((ext_vector_type(4))) float    f32x4;

#define MFMA16(a,b,c) __builtin_amdgcn_mfma_f32_16x16x32_f16(a,b,c,0,0,0)

__device__ __forceinline__ float sigm_hw(float x){
    float e = __builtin_amdgcn_exp2f(-1.442695041f * x);
    return __builtin_amdgcn_rcpf(1.0f + e);
}
__device__ __forceinline__ float tanh_hw(float x){
    float e = __builtin_amdgcn_exp2f(-2.885390082f * x);
    return fmaf(2.0f, __builtin_amdgcn_rcpf(1.0f + e), -1.0f);
}
__device__ __forceinline__ void splitF(float v, _Float16 &hi, _Float16 &lo){
    hi = (_Float16)v;
    lo = (_Float16)(v - (float)hi);
}
__device__ __forceinline__ f16x8 loadW8(const float* __restrict__ p){
    f16x8 r;
#pragma unroll
    for (int j=0;j<8;j++) r[j] = (_Float16)p[j];
    return r;
}
__device__ __forceinline__ unsigned short f2u(_Float16 h){ return __builtin_bit_cast(unsigned short, h); }
__device__ __forceinline__ _Float16 u2f(unsigned short u){ return __builtin_bit_cast(_Float16, u); }
__device__ __forceinline__ unsigned pack2(float a, float b){
    return (unsigned)f2u((_Float16)a) | ((unsigned)f2u((_Float16)b) << 16);
}
__device__ __forceinline__ float uf(unsigned u){ return __builtin_bit_cast(float, u); }
// LDS-only barrier: drains ds ops (lgkmcnt) but leaves global loads/stores in
// flight across the barrier. The compiler still inserts vmcnt waits before
// register USES of prefetched data; cross-launch ordering comes from
// kernel-dispatch boundaries. (R7 lesson: dispatch boundaries do this WITHOUT
// the device-scope L2 writeback+invalidate that grid.sync/__threadfence costs
// on non-coherent per-XCD L2s — persistent-kernel re-fetched 765MB/run.)
__device__ __forceinline__ void bar_lds(){
    asm volatile("s_waitcnt lgkmcnt(0)\n\ts_barrier" ::: "memory");
}

// LDS: h planes row-major [m][k] (136 = 128 + 8 pad). Double buffered; one
// lgkm-barrier per step.
struct SRec {
    alignas(16) _Float16 hH[2][16][136];
    alignas(16) _Float16 hL[2][16][136];
    alignas(16) float hf[16][132];         // head scratch
    alignas(16) float hf2[16][132];
};
struct SGem {
    alignas(16) _Float16 aH[2][16][136];
    alignas(16) _Float16 aL[2][16][136];
};
union SU { SRec r; SGem g; };

struct G3 { uint4 r, z, n; };   // f32 gx0 slot (48B)

// ---------------------------------------------------------------------------
// 256 blocks x 512 threads — the measured-best R2 configuration (8 waves,
// 2/SIMD, one sub per CU; every structural alternative measured worse:
// R3 1/SIMD -9%, R4 4/SIMD -45%, R6 kTc=16 -18%, R7 persistent -3x).
// Pipeline roles per launch (c = -1 .. kNCh+1):
//   blocks   0..63 : layer-0 GRU chunk c           (the serial pole)
//   blocks 64..191 : gx1 GEMM for chunk c-1  AND  gx0 GEMM for chunk c+1
//   blocks 192..255: layer-1 GRU chunk c-2 (+head on last)
// gx0[t] = Wih0·[x_t,emb] + bih0 is non-recurrent, precomputed one dispatch
// ahead and stored f32 (numerically identical up to reassociation).
// R8 rider: Whh0/Whh1 are prepacked to f16 ONCE at c=-1 (by the idle L0/L1
// blocks 0 and 192) into the workspace tail; the pole roles' prologues load
// 12x16B vectors instead of ~96 scalar f32 loads + converts per dispatch.
// Identical rounding (same cvt, done once). Tests whether P (~15.5us/dispatch)
// is prologue- or launch-dominated.
// In-lane gate update via MFMA C-layout: lane (lq,lm) reg q owns element
// (m=lq*4+q, i=16w+lm) of every gate tile simultaneously.
// ---------------------------------------------------------------------------
__attribute__((amdgpu_waves_per_eu(2, 2)))
__global__ void __launch_bounds__(512) rnn_fused(
    const float* __restrict__ x, const int* __restrict__ tick,
    const float* __restrict__ embed,
    const float* __restrict__ Wih0, const float* __restrict__ Whh0,
    const float* __restrict__ bih0, const float* __restrict__ bhh0,
    const float* __restrict__ Wih1, const float* __restrict__ bih1,
    const float* __restrict__ Whh1, const float* __restrict__ bhh1,
    const float* __restrict__ hw1, const float* __restrict__ hb1,
    const float* __restrict__ hw2, const float* __restrict__ hb2,
    unsigned* __restrict__ h0seq, unsigned* __restrict__ gxA,
    unsigned* __restrict__ gxB, float* __restrict__ h1state,
    unsigned* __restrict__ gx0, _Float16* __restrict__ wpk,
    float* __restrict__ out, int c)
{
    __shared__ SU sm;
    const int tid = threadIdx.x;
    const int w = tid >> 6, l = tid & 63, lm = l & 15, lq = l >> 4;
    const int i = 16*w + lm;                    // owned gate/hidden column
    const int cls[3] = { i, 128 + i, 256 + i }; // r/z/n weight rows

    if (blockIdx.x < 64) {
        // ================= layer-0 recurrence, chunk c =================
        if (c < 0 || c >= kNCh){
            // idle dispatch c=-1: block 0 prepacks Whh0 -> f16 (read from c=0 on)
            if (c == -1 && blockIdx.x == 0)
                for (int idx = tid; idx < 384*kH; idx += 512)
                    wpk[idx] = (_Float16)Whh0[idx];
            return;
        }
        SRec &S = sm.r;
        const int mb = blockIdx.x;
        unsigned* h0w = h0seq + (size_t)(c & 1) * kH0Str;
        const unsigned* g0 = gx0 + (size_t)(c & 1) * kGx0Str;

        f16x8 wv[3][4];
#pragma unroll
        for (int T=0; T<3; T++)
#pragma unroll
            for (int kt=0; kt<4; kt++)
                wv[T][kt] = *(const f16x8*)&wpk[(size_t)cls[T]*kH + kt*32 + lq*8];
        const float br = bhh0[cls[0]], bz = bhh0[cls[1]], bn = bhh0[cls[2]];

        // state init via ownership (covers all 16x128 exactly)
        float hreg[4];
        if (c == 0){
#pragma unroll
            for (int q=0;q<4;q++){
                hreg[q]=0.f;
                S.hH[0][lq*4+q][i]=(_Float16)0.f;
                S.hL[0][lq*4+q][i]=(_Float16)0.f;
            }
        } else {
            const unsigned* h0p = h0seq + (size_t)((c-1) & 1) * kH0Str;
#pragma unroll
            for (int q=0;q<4;q++){
                unsigned u = h0p[((size_t)(mb*kTc + kTc-1)*16 + lq*4+q)*kH + i];
                _Float16 hh = u2f((unsigned short)(u>>16)), hl = u2f((unsigned short)u);
                hreg[q] = (float)hh + (float)hl;
                S.hH[0][lq*4+q][i]=hh; S.hL[0][lq*4+q][i]=hl;
            }
        }
        // gx0 stream straight into registers (f32 r/z/n), 2-step prefetch
        const size_t base = (size_t)mb*kTc*512 + tid;
        auto ld3 = [&](size_t slot){
            G3 g; const unsigned* p = g0 + slot*12;
            g.r = *(const uint4*)p; g.z = *(const uint4*)(p+4); g.n = *(const uint4*)(p+8);
            return g;
        };
        G3 gc = ld3(base), gn = ld3(base + 512);
        bar_lds();

        int buf = 0;
        for (int tc=0; tc<kTc; tc++){
            const int nb = buf ^ 1;
            f16x8 aHf[4], aLf[4];
#pragma unroll
            for (int kt=0;kt<4;kt++){
                aHf[kt] = *(const f16x8*)&S.hH[buf][lm][kt*32 + lq*8];
                aLf[kt] = *(const f16x8*)&S.hL[buf][lm][kt*32 + lq*8];
            }
            f32x4 aR={br,br,br,br}, aZ={bz,bz,bz,bz}, aNH={bn,bn,bn,bn};
#pragma unroll
            for (int kt=0;kt<4;kt++){
                aR =MFMA16(aHf[kt],wv[0][kt],aR);  aR =MFMA16(aLf[kt],wv[0][kt],aR);
                aZ =MFMA16(aHf[kt],wv[1][kt],aZ);  aZ =MFMA16(aLf[kt],wv[1][kt],aZ);
                aNH=MFMA16(aHf[kt],wv[2][kt],aNH); aNH=MFMA16(aLf[kt],wv[2][kt],aNH);
            }
            const float rx[4] = { uf(gc.r.x), uf(gc.r.y), uf(gc.r.z), uf(gc.r.w) };
            const float zx[4] = { uf(gc.z.x), uf(gc.z.y), uf(gc.z.z), uf(gc.z.w) };
            const float nx[4] = { uf(gc.n.x), uf(gc.n.y), uf(gc.n.z), uf(gc.n.w) };
            // in-lane gate + state update (MFMA C regs stay local)
            unsigned pk[4];
#pragma unroll
            for (int q=0;q<4;q++){
                float r = sigm_hw(aR[q] + rx[q]);
                float z = sigm_hw(aZ[q] + zx[q]);
                float n = tanh_hw(fmaf(r, aNH[q], nx[q]));
                float h = fmaf(z, hreg[q]-n, n);
                hreg[q] = h;
                _Float16 hh,hl; splitF(h,hh,hl);
                S.hH[nb][lq*4+q][i]=hh;
                S.hL[nb][lq*4+q][i]=hl;
                pk[q] = ((unsigned)f2u(hh)<<16) | f2u(hl);
            }
#pragma unroll
            for (int q=0;q<4;q++)
                h0w[((size_t)(mb*kTc + tc)*16 + lq*4+q)*kH + i] = pk[q];
            gc = gn;
            int tn = tc + 2; if (tn > kTc-1) tn = kTc-1;
            gn = ld3(base + (size_t)tn*512);
            bar_lds();
            buf = nb;
        }
    } else if (blockIdx.x < 192) {
        // ============ gx GEMM blocks: gx1 for c-1, then gx0 for c+1 ============
        const int bid = blockIdx.x - 64;
        const int mb = bid >> 1, t0 = (bid & 1) * kTg;
        const int b0 = mb * kMB;
        const int g = c - 1;
        if (g >= 0 && g < kNCh) {
            SGem &S = sm.g;
            const unsigned* h0r = h0seq + (size_t)(g & 1) * kH0Str;
            unsigned* gA = gxA + (size_t)(g & 1) * kSlots * 4;
            unsigned* gB = gxB + (size_t)(g & 1) * kSlots * 2;

            f16x8 wv[3][4]; float bI[3];
#pragma unroll
            for (int T=0; T<3; T++){
#pragma unroll
                for (int kt=0; kt<4; kt++)
                    wv[T][kt] = loadW8(Wih1 + (size_t)cls[T]*kH + kt*32 + lq*8);
                bI[T] = bih1[cls[T]];
            }
            const int sr = tid >> 5, sq = tid & 31;   // staging role: row, u32-quad
            auto ld = [&](int t){
                return *(const uint4*)(h0r + ((size_t)(mb*kTc + t)*16 + sr)*kH + 4*sq);
            };
            auto stage = [&](int bf, uint4 u){
                f16x4 vh = { u2f((unsigned short)(u.x>>16)), u2f((unsigned short)(u.y>>16)),
                             u2f((unsigned short)(u.z>>16)), u2f((unsigned short)(u.w>>16)) };
                f16x4 vl = { u2f((unsigned short)u.x), u2f((unsigned short)u.y),
                             u2f((unsigned short)u.z), u2f((unsigned short)u.w) };
                *(f16x4*)&S.aH[bf][sr][4*sq] = vh;
                *(f16x4*)&S.aL[bf][sr][4*sq] = vl;
            };
            stage(0, ld(t0));
            uint4 nxt = ld(t0 + 1);
            bar_lds();
            for (int tt=0; tt<kTg; tt++){
                const int t = t0 + tt, bf = tt & 1;
                f16x8 fH[4], fL[4];
#pragma unroll
                for (int kt=0;kt<4;kt++){
                    fH[kt] = *(const f16x8*)&S.aH[bf][lm][kt*32 + lq*8];
                    fL[kt] = *(const f16x8*)&S.aL[bf][lm][kt*32 + lq*8];
                }
                if (tt+1 < kTg) stage(bf^1, nxt);
                if (tt+2 < kTg) nxt = ld(t0 + tt + 2);
                f32x4 aR = {bI[0],bI[0],bI[0],bI[0]};
                f32x4 aZ = {bI[1],bI[1],bI[1],bI[1]};
                f32x4 aN = {bI[2],bI[2],bI[2],bI[2]};
#pragma unroll
                for (int kt=0;kt<4;kt++){
                    aR=MFMA16(fH[kt],wv[0][kt],aR); aR=MFMA16(fL[kt],wv[0][kt],aR);
                    aZ=MFMA16(fH[kt],wv[1][kt],aZ); aZ=MFMA16(fL[kt],wv[1][kt],aZ);
                    aN=MFMA16(fH[kt],wv[2][kt],aN); aN=MFMA16(fL[kt],wv[2][kt],aN);
                }
                // store per-consumer-lane packed: l1 lane tid reads exactly this
                const size_t slot = ((size_t)mb*kTc + t)*512 + tid;
                *(uint4*)(gA + slot*4) = make_uint4(pack2(aR[0],aR[1]), pack2(aR[2],aR[3]),
                                                    pack2(aZ[0],aZ[1]), pack2(aZ[2],aZ[3]));
                *(uint2*)(gB + slot*2) = make_uint2(pack2(aN[0],aN[1]), pack2(aN[2],aN[3]));
                bar_lds();
            }
        }
        // ---- gx0 phase: layer-0 input gates for chunk p=c+1, f32, exact ----
        const int p = c + 1;
        if (p >= 0 && p < kNCh) {
            unsigned* g0w = gx0 + (size_t)(p & 1) * kGx0Str;
            f16x8 xw[3];
#pragma unroll
            for (int T=0; T<3; T++)
                xw[T] = loadW8(Wih0 + (size_t)cls[T]*48 + lq*8);
            float ini[3][4];
            {
                const float bi0 = bih0[cls[0]], bi1 = bih0[cls[1]], bi2 = bih0[cls[2]];
                const float* w0 = Wih0 + (size_t)cls[0]*48 + 32;
                const float* w1 = Wih0 + (size_t)cls[1]*48 + 32;
                const float* w2 = Wih0 + (size_t)cls[2]*48 + 32;
#pragma unroll
                for (int q=0; q<4; q++){
                    const float* ep = embed + (size_t)tick[b0 + lq*4 + q] * kE;
                    float s0=0.f, s1=0.f, s2=0.f;
#pragma unroll
                    for (int e=0; e<kE; e++){
                        float ev = ep[e];
                        s0 = fmaf(ev, w0[e], s0);
                        s1 = fmaf(ev, w1[e], s1);
                        s2 = fmaf(ev, w2[e], s2);
                    }
                    ini[0][q]=bi0+s0; ini[1][q]=bi1+s1; ini[2][q]=bi2+s2;
                }
            }
            // each wave loads its own A-fragment of x directly (rows lm,
            // cols lq*8..+7): 32B/lane, identical across waves -> cache hit
            for (int tt=0; tt<kTg; tt++){
                const int t = t0 + tt;
                const float* xp = x + (size_t)(b0+lm)*kT*kF + (size_t)(p*kTc + t)*kF + lq*8;
                const float4 xa = *(const float4*)xp;
                const float4 xb = *(const float4*)(xp + 4);
                const float xv[8] = { xa.x, xa.y, xa.z, xa.w, xb.x, xb.y, xb.z, xb.w };
                f16x8 xH, xL;
#pragma unroll
                for (int j=0;j<8;j++){
                    _Float16 hh,hl; splitF(xv[j],hh,hl);
                    xH[j]=hh; xL[j]=hl;
                }
                f32x4 aR = {ini[0][0],ini[0][1],ini[0][2],ini[0][3]};
                f32x4 aZ = {ini[1][0],ini[1][1],ini[1][2],ini[1][3]};
                f32x4 aN = {ini[2][0],ini[2][1],ini[2][2],ini[2][3]};
                aR=MFMA16(xH,xw[0],aR); aR=MFMA16(xL,xw[0],aR);
                aZ=MFMA16(xH,xw[1],aZ); aZ=MFMA16(xL,xw[1],aZ);
                aN=MFMA16(xH,xw[2],aN); aN=MFMA16(xL,xw[2],aN);
                const size_t slot = ((size_t)mb*kTc + t)*512 + tid;
                *(uint4*)(g0w + slot*12)     = __builtin_bit_cast(uint4, aR);
                *(uint4*)(g0w + slot*12 + 4) = __builtin_bit_cast(uint4, aZ);
                *(uint4*)(g0w + slot*12 + 8) = __builtin_bit_cast(uint4, aN);
            }
        }
    } else {
        // ================= layer-1 recurrence, chunk e0=c-2 =================
        const int e0 = c - 2;
        if (e0 < 0 || e0 >= kNCh){
            // idle dispatch c=-1: block 192 prepacks Whh1 -> f16
            if (c == -1 && blockIdx.x == 192)
                for (int idx = tid; idx < 384*kH; idx += 512)
                    wpk[384*kH + idx] = (_Float16)Whh1[idx];
            return;
        }
        SRec &S = sm.r;
        const int mb = blockIdx.x - 192, b0 = mb * kMB;
        const unsigned* gA = gxA + (size_t)(e0 & 1) * kSlots * 4;
        const unsigned* gB = gxB + (size_t)(e0 & 1) * kSlots * 2;

        f16x8 wv[3][4];
#pragma unroll
        for (int T=0; T<3; T++)
#pragma unroll
            for (int kt=0; kt<4; kt++)
                wv[T][kt] = *(const f16x8*)&wpk[384*kH + (size_t)cls[T]*kH + kt*32 + lq*8];
        const float br = bhh1[cls[0]], bz = bhh1[cls[1]], bn = bhh1[cls[2]];

        float hreg[4];
        if (e0 == 0){
#pragma unroll
            for (int q=0;q<4;q++){
                hreg[q]=0.f;
                S.hH[0][lq*4+q][i]=(_Float16)0.f;
                S.hL[0][lq*4+q][i]=(_Float16)0.f;
            }
        } else {
#pragma unroll
            for (int q=0;q<4;q++){
                float h = h1state[(size_t)(b0 + lq*4+q)*kH + i];
                hreg[q]=h;
                _Float16 hh,hl; splitF(h,hh,hl);
                S.hH[0][lq*4+q][i]=hh; S.hL[0][lq*4+q][i]=hl;
            }
        }
        // gx stream straight into registers, prefetched one step ahead
        const size_t base = (size_t)mb*kTc*512 + tid;
        uint4 g4c = *(const uint4*)(gA + base*4);
        uint2 g2c = *(const uint2*)(gB + base*2);
        uint4 g4n = *(const uint4*)(gA + (base + 512)*4);
        uint2 g2n = *(const uint2*)(gB + (base + 512)*2);
        bar_lds();

        int buf = 0;
        for (int tc=0; tc<kTc; tc++){
            const int nb = buf ^ 1;
            f16x8 aHf[4], aLf[4];
#pragma unroll
            for (int kt=0;kt<4;kt++){
                aHf[kt] = *(const f16x8*)&S.hH[buf][lm][kt*32 + lq*8];
                aLf[kt] = *(const f16x8*)&S.hL[buf][lm][kt*32 + lq*8];
            }
            f32x4 aR={br,br,br,br}, aZ={bz,bz,bz,bz}, aNH={bn,bn,bn,bn};
#pragma unroll
            for (int kt=0;kt<4;kt++){
                aR =MFMA16(aHf[kt],wv[0][kt],aR);  aR =MFMA16(aLf[kt],wv[0][kt],aR);
                aZ =MFMA16(aHf[kt],wv[1][kt],aZ);  aZ =MFMA16(aLf[kt],wv[1][kt],aZ);
                aNH=MFMA16(aHf[kt],wv[2][kt],aNH); aNH=MFMA16(aLf[kt],wv[2][kt],aNH);
            }
            const float rx[4] = { (float)u2f((unsigned short)g4c.x), (float)u2f((unsigned short)(g4c.x>>16)),
                                  (float)u2f((unsigned short)g4c.y), (float)u2f((unsigned short)(g4c.y>>16)) };
            const float zx[4] = { (float)u2f((unsigned short)g4c.z), (float)u2f((unsigned short)(g4c.z>>16)),
                                  (float)u2f((unsigned short)g4c.w), (float)u2f((unsigned short)(g4c.w>>16)) };
            const float nx[4] = { (float)u2f((unsigned short)g2c.x), (float)u2f((unsigned short)(g2c.x>>16)),
                                  (float)u2f((unsigned short)g2c.y), (float)u2f((unsigned short)(g2c.y>>16)) };
#pragma unroll
            for (int q=0;q<4;q++){
                float r = sigm_hw(aR[q] + rx[q]);
                float z = sigm_hw(aZ[q] + zx[q]);
                float n = tanh_hw(fmaf(r, aNH[q], nx[q]));
                float h = fmaf(z, hreg[q]-n, n);
                hreg[q] = h;
                _Float16 hh,hl; splitF(h,hh,hl);
                S.hH[nb][lq*4+q][i]=hh;
                S.hL[nb][lq*4+q][i]=hl;
            }
            g4c = g4n; g2c = g2n;
            int tn = tc + 2; if (tn > kTc-1) tn = kTc-1;
            g4n = *(const uint4*)(gA + (base + (size_t)tn*512)*4);
            g2n = *(const uint2*)(gB + (base + (size_t)tn*512)*2);
            bar_lds();
            buf = nb;
        }
#pragma unroll
        for (int q=0;q<4;q++)
            h1state[(size_t)(b0 + lq*4+q)*kH + i] = hreg[q];
        if (e0 == kNCh-1){
            // head: hid = relu(h1 @ hw1^T + hb1); y = hid @ hw2^T + hb2
#pragma unroll
            for (int q=0;q<4;q++) S.hf[lq*4+q][i] = hreg[q];
            __syncthreads();
            const int hm = tid >> 5, i0 = (tid & 31) * 4;
#pragma unroll
            for (int e=0;e<4;e++){
                const float* wr = hw1 + (size_t)(i0+e)*kH;
                float s = hb1[i0+e];
                for (int k2=0;k2<kH;k2++) s = fmaf(wr[k2], S.hf[hm][k2], s);
                S.hf2[hm][i0+e] = fmaxf(s, 0.f);
            }
            __syncthreads();
            if (tid < kMB){
                float s = hb2[0];
                for (int k2=0;k2<kH;k2++) s = fmaf(S.hf2[tid][k2], hw2[k2], s);
                out[b0 + tid] = s;
            }
        }
    }
}

extern "C" void kernel_launch(void* const* d_in, const int* in_sizes, int n_in,
                              void* d_out, int out_size, void* d_ws, size_t ws_size,
                              hipStream_t stream)
{
    const float* x     = (const float*)d_in[0];
    const int*   tick  = (const int*)d_in[1];
    const float* embed = (const float*)d_in[2];
    const float* Wih0  = (const float*)d_in[3];
    const float* Whh0  = (const float*)d_in[4];
    const float* bih0  = (const float*)d_in[5];
    const float* bhh0  = (const float*)d_in[6];
    const float* Wih1  = (const float*)d_in[7];
    const float* Whh1  = (const float*)d_in[8];
    const float* bih1  = (const float*)d_in[9];
    const float* bhh1  = (const float*)d_in[10];
    const float* hw1   = (const float*)d_in[11];
    const float* hb1   = (const float*)d_in[12];
    const float* hw2   = (const float*)d_in[13];
    const float* hb2   = (const float*)d_in[14];
    float* out = (float*)d_out;

    // ws: h0seq 2x16.8MB | gxA 2x16.8MB | gxB 2x8.4MB | h1state 0.5MB |
    //     gx0 2x50.3MB | wpk 196KB  ~ 185MB total
    unsigned* h0seq = (unsigned*)d_ws;
    unsigned* gxA   = h0seq + 2*kH0Str;
    unsigned* gxB   = gxA + 2*kSlots*4;
    float*  h1state = (float*)(gxB + 2*kSlots*2);
    unsigned* gx0   = (unsigned*)(h1state + (size_t)kB*kH);
    _Float16* wpk   = (_Float16*)(gx0 + 2*kGx0Str);

    for (int c = -1; c <= kNCh + 1; c++){
        rnn_fused<<<256, 512, 0, stream>>>(x, tick, embed,
            Wih0, Whh0, bih0, bhh0, Wih1, bih1, Whh1, bhh1,
            hw1, hb1, hw2, hb2, h0seq, gxA, gxB, h1state, gx0, wpk, out, c);
    }
}

// Round 9
// 1023.486 us; speedup vs baseline: 3.2231x; 1.0286x over previous
//
#include <hip/hip_runtime.h>

// Problem constants
constexpr int kB  = 1024;
constexpr int kT  = 512;
constexpr int kF  = 32;
constexpr int kE  = 16;
constexpr int kH  = 128;
constexpr int kMB = 16;             // batches per block (MFMA M)
constexpr int kNMB = kB / kMB;      // 64 batch tiles
constexpr int kTc = 32;             // chunk length (measured optimum)
constexpr int kNCh = kT / kTc;      // 16 chunks
constexpr int kTg = kTc / 2;        // t-steps per GEMM block
constexpr size_t kH0Str = (size_t)kB * kTc * kH;     // u32 per h0 chunk buffer
constexpr size_t kSlots = (size_t)kNMB * kTc * 512;  // gx lane-slots per chunk
constexpr size_t kGx0Str = kSlots * 12;              // u32 per gx0 chunk buffer

typedef __attribute__((ext_vector_type(8))) _Float16 f16x8;
typedef __attribute__((ext_vector_type(4))) _Float16 f16x4;
typedef __attribute__((ext_vector_type(4))) float    f32x4;

#define MFMA16(a,b,c) __builtin_amdgcn_mfma_f32_16x16x32_f16(a,b,c,0,0,0)

__device__ __forceinline__ float sigm_hw(float x){
    float e = __builtin_amdgcn_exp2f(-1.442695041f * x);
    return __builtin_amdgcn_rcpf(1.0f + e);
}
__device__ __forceinline__ float tanh_hw(float x){
    float e = __builtin_amdgcn_exp2f(-2.885390082f * x);
    return fmaf(2.0f, __builtin_amdgcn_rcpf(1.0f + e), -1.0f);
}
__device__ __forceinline__ void splitF(float v, _Float16 &hi, _Float16 &lo){
    hi = (_Float16)v;
    lo = (_Float16)(v - (float)hi);
}
__device__ __forceinline__ f16x8 loadW8(const float* __restrict__ p){
    f16x8 r;
#pragma unroll
    for (int j=0;j<8;j++) r[j] = (_Float16)p[j];
    return r;
}
__device__ __forceinline__ unsigned short f2u(_Float16 h){ return __builtin_bit_cast(unsigned short, h); }
__device__ __forceinline__ _Float16 u2f(unsigned short u){ return __builtin_bit_cast(_Float16, u); }
__device__ __forceinline__ unsigned pack2(float a, float b){
    return (unsigned)f2u((_Float16)a) | ((unsigned)f2u((_Float16)b) << 16);
}
__device__ __forceinline__ float uf(unsigned u){ return __builtin_bit_cast(float, u); }
// LDS-only barrier: drains ds ops (lgkmcnt) but leaves global loads/stores in
// flight across the barrier. The compiler still inserts vmcnt waits before
// register USES of prefetched data; cross-launch ordering comes from
// kernel-dispatch boundaries. (R7 lesson: dispatch boundaries do this WITHOUT
// the device-scope L2 writeback+invalidate that grid.sync/__threadfence costs
// on non-coherent per-XCD L2s — persistent-kernel re-fetched 765MB/run.)
__device__ __forceinline__ void bar_lds(){
    asm volatile("s_waitcnt lgkmcnt(0)\n\ts_barrier" ::: "memory");
}

// LDS: h planes row-major [m][k] (136 = 128 + 8 pad). Double buffered; one
// lgkm-barrier per step.
struct SRec {
    alignas(16) _Float16 hH[2][16][136];
    alignas(16) _Float16 hL[2][16][136];
    alignas(16) float hf[16][132];         // head scratch
    alignas(16) float hf2[16][132];
};
struct SGem {
    alignas(16) _Float16 aH[2][16][136];
    alignas(16) _Float16 aL[2][16][136];
};
union SU { SRec r; SGem g; };

struct G3 { uint4 r, z, n; };   // f32 gx0 slot (48B)

// ---------------------------------------------------------------------------
// 256 blocks x 512 threads — the measured-best configuration (8 waves,
// 2/SIMD, one sub per CU; every structural alternative measured worse:
// R3 1/SIMD -9%, R4 4/SIMD -45%, R6 kTc=16 -18%, R7 persistent -3x;
// depth-2 pipeline rejected by arithmetic: -1 dispatch but +24 MFMA issue
// x16 dispatches on the new pole ~ net -7us at spill risk).
// Pipeline roles per launch (c = -1 .. kNCh+1):
//   blocks   0..63 : layer-0 GRU chunk c           (the serial pole)
//   blocks 64..191 : gx1 GEMM for chunk c-1  AND  gx0 GEMM for chunk c+1
//   blocks 192..255: layer-1 GRU chunk c-2 (+head on last)
// gx0[t] = Wih0·[x_t,emb] + bih0 is non-recurrent, precomputed one dispatch
// ahead and stored f32 (numerically identical up to reassociation).
// Weight prepack (R8/R9): Whh0/Whh1/Wih1 converted to f16 ONCE at c=-1 by
// idle blocks {0, 192, 1} into the workspace tail; recurrence + gx1
// prologues load 12x16B vectors instead of ~96 scalar f32 loads + converts
// per dispatch. Identical rounding (same cvt, done once).
// In-lane gate update via MFMA C-layout: lane (lq,lm) reg q owns element
// (m=lq*4+q, i=16w+lm) of every gate tile simultaneously.
// ---------------------------------------------------------------------------
__attribute__((amdgpu_waves_per_eu(2, 2)))
__global__ void __launch_bounds__(512) rnn_fused(
    const float* __restrict__ x, const int* __restrict__ tick,
    const float* __restrict__ embed,
    const float* __restrict__ Wih0, const float* __restrict__ Whh0,
    const float* __restrict__ bih0, const float* __restrict__ bhh0,
    const float* __restrict__ Wih1, const float* __restrict__ bih1,
    const float* __restrict__ Whh1, const float* __restrict__ bhh1,
    const float* __restrict__ hw1, const float* __restrict__ hb1,
    const float* __restrict__ hw2, const float* __restrict__ hb2,
    unsigned* __restrict__ h0seq, unsigned* __restrict__ gxA,
    unsigned* __restrict__ gxB, float* __restrict__ h1state,
    unsigned* __restrict__ gx0, _Float16* __restrict__ wpk,
    float* __restrict__ out, int c)
{
    __shared__ SU sm;
    const int tid = threadIdx.x;
    const int w = tid >> 6, l = tid & 63, lm = l & 15, lq = l >> 4;
    const int i = 16*w + lm;                    // owned gate/hidden column
    const int cls[3] = { i, 128 + i, 256 + i }; // r/z/n weight rows

    if (blockIdx.x < 64) {
        // ================= layer-0 recurrence, chunk c =================
        if (c < 0 || c >= kNCh){
            // idle dispatch c=-1: block 0 prepacks Whh0, block 1 prepacks Wih1
            if (c == -1 && blockIdx.x == 0)
                for (int idx = tid; idx < 384*kH; idx += 512)
                    wpk[idx] = (_Float16)Whh0[idx];
            if (c == -1 && blockIdx.x == 1)
                for (int idx = tid; idx < 384*kH; idx += 512)
                    wpk[768*kH + idx] = (_Float16)Wih1[idx];
            return;
        }
        SRec &S = sm.r;
        const int mb = blockIdx.x;
        unsigned* h0w = h0seq + (size_t)(c & 1) * kH0Str;
        const unsigned* g0 = gx0 + (size_t)(c & 1) * kGx0Str;

        // --- issue latency-critical prologue loads FIRST (state + stream) ---
        float hreg[4];
        if (c == 0){
#pragma unroll
            for (int q=0;q<4;q++){
                hreg[q]=0.f;
                S.hH[0][lq*4+q][i]=(_Float16)0.f;
                S.hL[0][lq*4+q][i]=(_Float16)0.f;
            }
        } else {
            const unsigned* h0p = h0seq + (size_t)((c-1) & 1) * kH0Str;
#pragma unroll
            for (int q=0;q<4;q++){
                unsigned u = h0p[((size_t)(mb*kTc + kTc-1)*16 + lq*4+q)*kH + i];
                _Float16 hh = u2f((unsigned short)(u>>16)), hl = u2f((unsigned short)u);
                hreg[q] = (float)hh + (float)hl;
                S.hH[0][lq*4+q][i]=hh; S.hL[0][lq*4+q][i]=hl;
            }
        }
        // gx0 stream straight into registers (f32 r/z/n), 2-step prefetch
        const size_t base = (size_t)mb*kTc*512 + tid;
        auto ld3 = [&](size_t slot){
            G3 g; const unsigned* p = g0 + slot*12;
            g.r = *(const uint4*)p; g.z = *(const uint4*)(p+4); g.n = *(const uint4*)(p+8);
            return g;
        };
        G3 gc = ld3(base), gn = ld3(base + 512);

        f16x8 wv[3][4];
#pragma unroll
        for (int T=0; T<3; T++)
#pragma unroll
            for (int kt=0; kt<4; kt++)
                wv[T][kt] = *(const f16x8*)&wpk[(size_t)cls[T]*kH + kt*32 + lq*8];
        const float br = bhh0[cls[0]], bz = bhh0[cls[1]], bn = bhh0[cls[2]];
        bar_lds();

        int buf = 0;
        for (int tc=0; tc<kTc; tc++){
            const int nb = buf ^ 1;
            f16x8 aHf[4], aLf[4];
#pragma unroll
            for (int kt=0;kt<4;kt++){
                aHf[kt] = *(const f16x8*)&S.hH[buf][lm][kt*32 + lq*8];
                aLf[kt] = *(const f16x8*)&S.hL[buf][lm][kt*32 + lq*8];
            }
            f32x4 aR={br,br,br,br}, aZ={bz,bz,bz,bz}, aNH={bn,bn,bn,bn};
#pragma unroll
            for (int kt=0;kt<4;kt++){
                aR =MFMA16(aHf[kt],wv[0][kt],aR);  aR =MFMA16(aLf[kt],wv[0][kt],aR);
                aZ =MFMA16(aHf[kt],wv[1][kt],aZ);  aZ =MFMA16(aLf[kt],wv[1][kt],aZ);
                aNH=MFMA16(aHf[kt],wv[2][kt],aNH); aNH=MFMA16(aLf[kt],wv[2][kt],aNH);
            }
            const float rx[4] = { uf(gc.r.x), uf(gc.r.y), uf(gc.r.z), uf(gc.r.w) };
            const float zx[4] = { uf(gc.z.x), uf(gc.z.y), uf(gc.z.z), uf(gc.z.w) };
            const float nx[4] = { uf(gc.n.x), uf(gc.n.y), uf(gc.n.z), uf(gc.n.w) };
            // in-lane gate + state update (MFMA C regs stay local)
            unsigned pk[4];
#pragma unroll
            for (int q=0;q<4;q++){
                float r = sigm_hw(aR[q] + rx[q]);
                float z = sigm_hw(aZ[q] + zx[q]);
                float n = tanh_hw(fmaf(r, aNH[q], nx[q]));
                float h = fmaf(z, hreg[q]-n, n);
                hreg[q] = h;
                _Float16 hh,hl; splitF(h,hh,hl);
                S.hH[nb][lq*4+q][i]=hh;
                S.hL[nb][lq*4+q][i]=hl;
                pk[q] = ((unsigned)f2u(hh)<<16) | f2u(hl);
            }
#pragma unroll
            for (int q=0;q<4;q++)
                h0w[((size_t)(mb*kTc + tc)*16 + lq*4+q)*kH + i] = pk[q];
            gc = gn;
            int tn = tc + 2; if (tn > kTc-1) tn = kTc-1;
            gn = ld3(base + (size_t)tn*512);
            bar_lds();
            buf = nb;
        }
    } else if (blockIdx.x < 192) {
        // ============ gx GEMM blocks: gx1 for c-1, then gx0 for c+1 ============
        const int bid = blockIdx.x - 64;
        const int mb = bid >> 1, t0 = (bid & 1) * kTg;
        const int b0 = mb * kMB;
        const int g = c - 1;
        if (g >= 0 && g < kNCh) {
            SGem &S = sm.g;
            const unsigned* h0r = h0seq + (size_t)(g & 1) * kH0Str;
            unsigned* gA = gxA + (size_t)(g & 1) * kSlots * 4;
            unsigned* gB = gxB + (size_t)(g & 1) * kSlots * 2;

            // Wih1 prepacked at c=-1 (first use here is c=1) -> vector loads
            f16x8 wv[3][4]; float bI[3];
#pragma unroll
            for (int T=0; T<3; T++){
#pragma unroll
                for (int kt=0; kt<4; kt++)
                    wv[T][kt] = *(const f16x8*)&wpk[768*kH + (size_t)cls[T]*kH + kt*32 + lq*8];
                bI[T] = bih1[cls[T]];
            }
            const int sr = tid >> 5, sq = tid & 31;   // staging role: row, u32-quad
            auto ld = [&](int t){
                return *(const uint4*)(h0r + ((size_t)(mb*kTc + t)*16 + sr)*kH + 4*sq);
            };
            auto stage = [&](int bf, uint4 u){
                f16x4 vh = { u2f((unsigned short)(u.x>>16)), u2f((unsigned short)(u.y>>16)),
                             u2f((unsigned short)(u.z>>16)), u2f((unsigned short)(u.w>>16)) };
                f16x4 vl = { u2f((unsigned short)u.x), u2f((unsigned short)u.y),
                             u2f((unsigned short)u.z), u2f((unsigned short)u.w) };
                *(f16x4*)&S.aH[bf][sr][4*sq] = vh;
                *(f16x4*)&S.aL[bf][sr][4*sq] = vl;
            };
            stage(0, ld(t0));
            uint4 nxt = ld(t0 + 1);
            bar_lds();
            for (int tt=0; tt<kTg; tt++){
                const int t = t0 + tt, bf = tt & 1;
                f16x8 fH[4], fL[4];
#pragma unroll
                for (int kt=0;kt<4;kt++){
                    fH[kt] = *(const f16x8*)&S.aH[bf][lm][kt*32 + lq*8];
                    fL[kt] = *(const f16x8*)&S.aL[bf][lm][kt*32 + lq*8];
                }
                if (tt+1 < kTg) stage(bf^1, nxt);
                if (tt+2 < kTg) nxt = ld(t0 + tt + 2);
                f32x4 aR = {bI[0],bI[0],bI[0],bI[0]};
                f32x4 aZ = {bI[1],bI[1],bI[1],bI[1]};
                f32x4 aN = {bI[2],bI[2],bI[2],bI[2]};
#pragma unroll
                for (int kt=0;kt<4;kt++){
                    aR=MFMA16(fH[kt],wv[0][kt],aR); aR=MFMA16(fL[kt],wv[0][kt],aR);
                    aZ=MFMA16(fH[kt],wv[1][kt],aZ); aZ=MFMA16(fL[kt],wv[1][kt],aZ);
                    aN=MFMA16(fH[kt],wv[2][kt],aN); aN=MFMA16(fL[kt],wv[2][kt],aN);
                }
                // store per-consumer-lane packed: l1 lane tid reads exactly this
                const size_t slot = ((size_t)mb*kTc + t)*512 + tid;
                *(uint4*)(gA + slot*4) = make_uint4(pack2(aR[0],aR[1]), pack2(aR[2],aR[3]),
                                                    pack2(aZ[0],aZ[1]), pack2(aZ[2],aZ[3]));
                *(uint2*)(gB + slot*2) = make_uint2(pack2(aN[0],aN[1]), pack2(aN[2],aN[3]));
                bar_lds();
            }
        }
        // ---- gx0 phase: layer-0 input gates for chunk p=c+1, f32, exact ----
        const int p = c + 1;
        if (p >= 0 && p < kNCh) {
            unsigned* g0w = gx0 + (size_t)(p & 1) * kGx0Str;
            f16x8 xw[3];
#pragma unroll
            for (int T=0; T<3; T++)
                xw[T] = loadW8(Wih0 + (size_t)cls[T]*48 + lq*8);
            float ini[3][4];
            {
                const float bi0 = bih0[cls[0]], bi1 = bih0[cls[1]], bi2 = bih0[cls[2]];
                const float* w0 = Wih0 + (size_t)cls[0]*48 + 32;
                const float* w1 = Wih0 + (size_t)cls[1]*48 + 32;
                const float* w2 = Wih0 + (size_t)cls[2]*48 + 32;
#pragma unroll
                for (int q=0; q<4; q++){
                    const float* ep = embed + (size_t)tick[b0 + lq*4 + q] * kE;
                    float s0=0.f, s1=0.f, s2=0.f;
#pragma unroll
                    for (int e=0; e<kE; e++){
                        float ev = ep[e];
                        s0 = fmaf(ev, w0[e], s0);
                        s1 = fmaf(ev, w1[e], s1);
                        s2 = fmaf(ev, w2[e], s2);
                    }
                    ini[0][q]=bi0+s0; ini[1][q]=bi1+s1; ini[2][q]=bi2+s2;
                }
            }
            // each wave loads its own A-fragment of x directly (rows lm,
            // cols lq*8..+7): 32B/lane, identical across waves -> cache hit
            for (int tt=0; tt<kTg; tt++){
                const int t = t0 + tt;
                const float* xp = x + (size_t)(b0+lm)*kT*kF + (size_t)(p*kTc + t)*kF + lq*8;
                const float4 xa = *(const float4*)xp;
                const float4 xb = *(const float4*)(xp + 4);
                const float xv[8] = { xa.x, xa.y, xa.z, xa.w, xb.x, xb.y, xb.z, xb.w };
                f16x8 xH, xL;
#pragma unroll
                for (int j=0;j<8;j++){
                    _Float16 hh,hl; splitF(xv[j],hh,hl);
                    xH[j]=hh; xL[j]=hl;
                }
                f32x4 aR = {ini[0][0],ini[0][1],ini[0][2],ini[0][3]};
                f32x4 aZ = {ini[1][0],ini[1][1],ini[1][2],ini[1][3]};
                f32x4 aN = {ini[2][0],ini[2][1],ini[2][2],ini[2][3]};
                aR=MFMA16(xH,xw[0],aR); aR=MFMA16(xL,xw[0],aR);
                aZ=MFMA16(xH,xw[1],aZ); aZ=MFMA16(xL,xw[1],aZ);
                aN=MFMA16(xH,xw[2],aN); aN=MFMA16(xL,xw[2],aN);
                const size_t slot = ((size_t)mb*kTc + t)*512 + tid;
                *(uint4*)(g0w + slot*12)     = __builtin_bit_cast(uint4, aR);
                *(uint4*)(g0w + slot*12 + 4) = __builtin_bit_cast(uint4, aZ);
                *(uint4*)(g0w + slot*12 + 8) = __builtin_bit_cast(uint4, aN);
            }
        }
    } else {
        // ================= layer-1 recurrence, chunk e0=c-2 =================
        const int e0 = c - 2;
        if (e0 < 0 || e0 >= kNCh){
            // idle dispatch c=-1: block 192 prepacks Whh1 -> f16
            if (c == -1 && blockIdx.x == 192)
                for (int idx = tid; idx < 384*kH; idx += 512)
                    wpk[384*kH + idx] = (_Float16)Whh1[idx];
            return;
        }
        SRec &S = sm.r;
        const int mb = blockIdx.x - 192, b0 = mb * kMB;
        const unsigned* gA = gxA + (size_t)(e0 & 1) * kSlots * 4;
        const unsigned* gB = gxB + (size_t)(e0 & 1) * kSlots * 2;

        // --- latency-critical prologue loads first (state + stream) ---
        float hreg[4];
        if (e0 == 0){
#pragma unroll
            for (int q=0;q<4;q++){
                hreg[q]=0.f;
                S.hH[0][lq*4+q][i]=(_Float16)0.f;
                S.hL[0][lq*4+q][i]=(_Float16)0.f;
            }
        } else {
#pragma unroll
            for (int q=0;q<4;q++){
                float h = h1state[(size_t)(b0 + lq*4+q)*kH + i];
                hreg[q]=h;
                _Float16 hh,hl; splitF(h,hh,hl);
                S.hH[0][lq*4+q][i]=hh; S.hL[0][lq*4+q][i]=hl;
            }
        }
        // gx stream straight into registers, prefetched one step ahead
        const size_t base = (size_t)mb*kTc*512 + tid;
        uint4 g4c = *(const uint4*)(gA + base*4);
        uint2 g2c = *(const uint2*)(gB + base*2);
        uint4 g4n = *(const uint4*)(gA + (base + 512)*4);
        uint2 g2n = *(const uint2*)(gB + (base + 512)*2);

        f16x8 wv[3][4];
#pragma unroll
        for (int T=0; T<3; T++)
#pragma unroll
            for (int kt=0; kt<4; kt++)
                wv[T][kt] = *(const f16x8*)&wpk[384*kH + (size_t)cls[T]*kH + kt*32 + lq*8];
        const float br = bhh1[cls[0]], bz = bhh1[cls[1]], bn = bhh1[cls[2]];
        bar_lds();

        int buf = 0;
        for (int tc=0; tc<kTc; tc++){
            const int nb = buf ^ 1;
            f16x8 aHf[4], aLf[4];
#pragma unroll
            for (int kt=0;kt<4;kt++){
                aHf[kt] = *(const f16x8*)&S.hH[buf][lm][kt*32 + lq*8];
                aLf[kt] = *(const f16x8*)&S.hL[buf][lm][kt*32 + lq*8];
            }
            f32x4 aR={br,br,br,br}, aZ={bz,bz,bz,bz}, aNH={bn,bn,bn,bn};
#pragma unroll
            for (int kt=0;kt<4;kt++){
                aR =MFMA16(aHf[kt],wv[0][kt],aR);  aR =MFMA16(aLf[kt],wv[0][kt],aR);
                aZ =MFMA16(aHf[kt],wv[1][kt],aZ);  aZ =MFMA16(aLf[kt],wv[1][kt],aZ);
                aNH=MFMA16(aHf[kt],wv[2][kt],aNH); aNH=MFMA16(aLf[kt],wv[2][kt],aNH);
            }
            const float rx[4] = { (float)u2f((unsigned short)g4c.x), (float)u2f((unsigned short)(g4c.x>>16)),
                                  (float)u2f((unsigned short)g4c.y), (float)u2f((unsigned short)(g4c.y>>16)) };
            const float zx[4] = { (float)u2f((unsigned short)g4c.z), (float)u2f((unsigned short)(g4c.z>>16)),
                                  (float)u2f((unsigned short)g4c.w), (float)u2f((unsigned short)(g4c.w>>16)) };
            const float nx[4] = { (float)u2f((unsigned short)g2c.x), (float)u2f((unsigned short)(g2c.x>>16)),
                                  (float)u2f((unsigned short)g2c.y), (float)u2f((unsigned short)(g2c.y>>16)) };
#pragma unroll
            for (int q=0;q<4;q++){
                float r = sigm_hw(aR[q] + rx[q]);
                float z = sigm_hw(aZ[q] + zx[q]);
                float n = tanh_hw(fmaf(r, aNH[q], nx[q]));
                float h = fmaf(z, hreg[q]-n, n);
                hreg[q] = h;
                _Float16 hh,hl; splitF(h,hh,hl);
                S.hH[nb][lq*4+q][i]=hh;
                S.hL[nb][lq*4+q][i]=hl;
            }
            g4c = g4n; g2c = g2n;
            int tn = tc + 2; if (tn > kTc-1) tn = kTc-1;
            g4n = *(const uint4*)(gA + (base + (size_t)tn*512)*4);
            g2n = *(const uint2*)(gB + (base + (size_t)tn*512)*2);
            bar_lds();
            buf = nb;
        }
#pragma unroll
        for (int q=0;q<4;q++)
            h1state[(size_t)(b0 + lq*4+q)*kH + i] = hreg[q];
        if (e0 == kNCh-1){
            // head: hid = relu(h1 @ hw1^T + hb1); y = hid @ hw2^T + hb2
#pragma unroll
            for (int q=0;q<4;q++) S.hf[lq*4+q][i] = hreg[q];
            __syncthreads();
            const int hm = tid >> 5, i0 = (tid & 31) * 4;
#pragma unroll
            for (int e=0;e<4;e++){
                const float* wr = hw1 + (size_t)(i0+e)*kH;
                float s = hb1[i0+e];
                for (int k2=0;k2<kH;k2++) s = fmaf(wr[k2], S.hf[hm][k2], s);
                S.hf2[hm][i0+e] = fmaxf(s, 0.f);
            }
            __syncthreads();
            if (tid < kMB){
                float s = hb2[0];
                for (int k2=0;k2<kH;k2++) s = fmaf(S.hf2[tid][k2], hw2[k2], s);
                out[b0 + tid] = s;
            }
        }
    }
}

extern "C" void kernel_launch(void* const* d_in, const int* in_sizes, int n_in,
                              void* d_out, int out_size, void* d_ws, size_t ws_size,
                              hipStream_t stream)
{
    const float* x     = (const float*)d_in[0];
    const int*   tick  = (const int*)d_in[1];
    const float* embed = (const float*)d_in[2];
    const float* Wih0  = (const float*)d_in[3];
    const float* Whh0  = (const float*)d_in[4];
    const float* bih0  = (const float*)d_in[5];
    const float* bhh0  = (const float*)d_in[6];
    const float* Wih1  = (const float*)d_in[7];
    const float* Whh1  = (const float*)d_in[8];
    const float* bih1  = (const float*)d_in[9];
    const float* bhh1  = (const float*)d_in[10];
    const float* hw1   = (const float*)d_in[11];
    const float* hb1   = (const float*)d_in[12];
    const float* hw2   = (const float*)d_in[13];
    const float* hb2   = (const float*)d_in[14];
    float* out = (float*)d_out;

    // ws: h0seq 2x16.8MB | gxA 2x16.8MB | gxB 2x8.4MB | h1state 0.5MB |
    //     gx0 2x50.3MB | wpk 288KB  ~ 185MB total
    unsigned* h0seq = (unsigned*)d_ws;
    unsigned* gxA   = h0seq + 2*kH0Str;
    unsigned* gxB   = gxA + 2*kSlots*4;
    float*  h1state = (float*)(gxB + 2*kSlots*2);
    unsigned* gx0   = (unsigned*)(h1state + (size_t)kB*kH);
    _Float16* wpk   = (_Float16*)(gx0 + 2*kGx0Str);

    for (int c = -1; c <= kNCh + 1; c++){
        rnn_fused<<<256, 512, 0, stream>>>(x, tick, embed,
            Wih0, Whh0, bih0, bhh0, Wih1, bih1, Whh1, bhh1,
            hw1, hb1, hw2, hb2, h0seq, gxA, gxB, h1state, gx0, wpk, out, c);
    }
}